// Round 2
// baseline (185.571 us; speedup 1.0000x reference)
//
#include <hip/hip_runtime.h>

// LBP uniform P=8 R=1 on (32,3,512,512) f32, zero-padded borders.
// R4b: LDS-staged 64x64 tile per block (+1 halo ring), pre-QUANTIZED at stage
// time. (R4 failed to compile: __builtin_nontemporal_store rejects the
// HIP_vector_type float4; use a clang ext_vector_type(4) float instead.)
// Rationale vs R3:
//   - R3 issued 18 VMEM/thread incl. 12 stride-16B scalar edge loads (25%
//     sector efficiency) and quantized 36 values per 16 px (2.25x redundant).
//   - R4: all global reads are coalesced float4 (halo amp 1.06x), ~4.7
//     VMEM/thread, each input element quantized exactly once, no per-value
//     OOB cndmasks in the hot phase. LDS = 66 rows x 72 words = 19 KB.
//   - Output stores nontemporal: 100 MB write stream shouldn't evict halo.

#define LBP_H 512
#define LBP_W 512
#define NPLANES 96           // 32 * 3
#define TDIM 64              // output tile is 64x64 per block
#define LROWS 66             // tile rows + halo
#define LDSW 72              // word stride per LDS row (word 3 = left halo,
                             // words 4..67 = interior, word 68 = right halo)

typedef float f32x4 __attribute__((ext_vector_type(4)));

__device__ __forceinline__ float lbp_quant(float v) {
    // == jnp.clip(jnp.floor(x*255), 0, 255) in exact fp32 arithmetic
    return fminf(fmaxf(floorf(v * 255.0f), 0.0f), 255.0f);
}

__global__ __launch_bounds__(256, 4) void lbp_kernel(const float* __restrict__ x,
                                                     float* __restrict__ out) {
    __shared__ __align__(16) float lds[LROWS * LDSW];

    const int tid   = threadIdx.x;
    const int bid   = blockIdx.x;
    const int plane = bid >> 6;          // 0..95
    const int t     = bid & 63;          // 8x8 tiles per plane
    const int R0    = (t >> 3) << 6;     // tile row origin
    const int C0    = (t & 7) << 6;      // tile col origin

    const float* base = x + (size_t)plane * (LBP_H * LBP_W);

    // ---- stage interior: 66 rows x 16 float4 = 1056 slots, quantized ----
#pragma unroll
    for (int k = 0; k < 5; ++k) {
        const int slot = tid + (k << 8);
        if (slot < 1056) {
            const int rr = slot >> 4;        // 0..65  (lds row)
            const int q  = slot & 15;        // 0..15  (float4 within row)
            const int g  = R0 - 1 + rr;      // global row, may be OOB
            f32x4 vv = (f32x4)(0.0f);
            if ((unsigned)g < LBP_H)
                vv = *(const f32x4*)(base + (size_t)g * LBP_W + C0 + (q << 2));
            f32x4 qv;
            qv.x = lbp_quant(vv.x);
            qv.y = lbp_quant(vv.y);
            qv.z = lbp_quant(vv.z);
            qv.w = lbp_quant(vv.w);
            *(f32x4*)(&lds[rr * LDSW + 4 + (q << 2)]) = qv;  // 16B aligned
        }
    }

    // ---- stage left/right halo columns: 66 rows x 2 = 132 scalars ----
    if (tid < 132) {
        const int rr    = tid >> 1;
        const int right = tid & 1;
        const int g     = R0 - 1 + rr;
        const int col   = right ? (C0 + TDIM) : (C0 - 1);
        float v = 0.f;
        if ((unsigned)g < LBP_H && (unsigned)col < LBP_W)
            v = base[(size_t)g * LBP_W + col];
        lds[rr * LDSW + (right ? (4 + TDIM) : 3)] = lbp_quant(v);
    }

    __syncthreads();

    // ---- compute: thread (tr,tc) owns 4x4 output pixels ----
    const int tc = tid & 15;             // 0..15 -> cols C0 + tc*4 .. +3
    const int tr = tid >> 4;             // 0..15 -> rows R0 + tr*4 .. +3

    // e[r][k]: quantized value at global row R0-1+tr*4+r, col C0-1+tc*4+k
    float e[6][6];
#pragma unroll
    for (int r = 0; r < 6; ++r) {
        const float* lp = &lds[((tr << 2) + r) * LDSW + (tc << 2)];
        e[r][0] = lp[3];
        const f32x4 m = *(const f32x4*)(lp + 4);   // 16B aligned
        e[r][1] = m.x; e[r][2] = m.y; e[r][3] = m.z; e[r][4] = m.w;
        e[r][5] = lp[8];
    }

    float* obase = out + (size_t)plane * (LBP_H * LBP_W)
                       + (size_t)(R0 + (tr << 2)) * LBP_W + C0 + (tc << 2);

#pragma unroll
    for (int p = 0; p < 4; ++p) {             // output row offset
        f32x4 o;
#pragma unroll
        for (int c = 0; c < 4; ++c) {         // output col offset
            const float ctr = e[p + 1][c + 1];
            // circular order: (-1,-1),(-1,0),(-1,1),(0,1),(1,1),(1,0),(1,-1),(0,-1)
            unsigned m = 0u;
            m |= (e[p    ][c    ] >= ctr) ?   1u : 0u;
            m |= (e[p    ][c + 1] >= ctr) ?   2u : 0u;
            m |= (e[p    ][c + 2] >= ctr) ?   4u : 0u;
            m |= (e[p + 1][c + 2] >= ctr) ?   8u : 0u;
            m |= (e[p + 2][c + 2] >= ctr) ?  16u : 0u;
            m |= (e[p + 2][c + 1] >= ctr) ?  32u : 0u;
            m |= (e[p + 2][c    ] >= ctr) ?  64u : 0u;
            m |= (e[p + 1][c    ] >= ctr) ? 128u : 0u;
            const unsigned rot = ((m >> 1) | (m << 7)) & 255u;
            const int trans = __popc(m ^ rot);
            const int val = (trans <= 2) ? __popc(m) : 9;
            o[c] = (float)val * (1.0f / 255.0f);
        }
        __builtin_nontemporal_store(o, (f32x4*)(obase + (size_t)p * LBP_W));
    }
}

extern "C" void kernel_launch(void* const* d_in, const int* in_sizes, int n_in,
                              void* d_out, int out_size, void* d_ws, size_t ws_size,
                              hipStream_t stream) {
    const float* x = (const float*)d_in[0];
    float* out = (float*)d_out;
    const int blocks = NPLANES * 64;      // 96 planes x (8x8 tiles) = 6144
    lbp_kernel<<<blocks, 256, 0, stream>>>(x, out);
}